// Round 16
// baseline (5253.055 us; speedup 1.0000x reference)
//
#include <hip/hip_runtime.h>
#include <math.h>

#define BATCH 32
#define TLEN  512
#define HID   1024
#define G2    2048   // 2*H
#define BHID (BATCH * HID)

typedef _Float16 half8 __attribute__((ext_vector_type(8)));
typedef float f32x4 __attribute__((ext_vector_type(4)));

// ---------------------------------------------------------------------------
// fp32 -> fp16 conversion (8 elems/thread)
// ---------------------------------------------------------------------------
__global__ __launch_bounds__(256)
void conv_f16(const float* __restrict__ s, _Float16* __restrict__ d, int n8) {
    int i = blockIdx.x * 256 + threadIdx.x;
    if (i < n8) {
        int base = i * 8;
        float4 v0 = *(const float4*)&s[base];
        float4 v1 = *(const float4*)&s[base + 4];
        half8 h;
        h[0] = (_Float16)v0.x; h[1] = (_Float16)v0.y;
        h[2] = (_Float16)v0.z; h[3] = (_Float16)v0.w;
        h[4] = (_Float16)v1.x; h[5] = (_Float16)v1.y;
        h[6] = (_Float16)v1.z; h[7] = (_Float16)v1.w;
        *(half8*)&d[base] = h;
    }
}

// ---------------------------------------------------------------------------
// MFMA projection GEMM (proven R11-R15): Cw[t][b][n] = sum_k A[m][k]*W[n][k],
// m = b*T + t. fp16 in, fp16 out.
// ---------------------------------------------------------------------------
__global__ __launch_bounds__(256)
void proj_gemm_f16(const _Float16* __restrict__ A, const _Float16* __restrict__ W,
                   _Float16* __restrict__ Cw, int K) {
    const int tid = threadIdx.x;
    const int wv = tid >> 6;
    const int l  = tid & 63;
    const int m0 = blockIdx.x * 128 + (wv >> 1) * 64;
    const int n0 = blockIdx.y * 128 + (wv & 1) * 64;
    const int fr = l & 15;
    const int kg = l >> 4;

    f32x4 acc[4][4];
    #pragma unroll
    for (int i = 0; i < 4; ++i)
        #pragma unroll
        for (int j = 0; j < 4; ++j) acc[i][j] = (f32x4){0.f, 0.f, 0.f, 0.f};

    const int nkc = K >> 5;
    #pragma unroll 2
    for (int kc = 0; kc < nkc; ++kc) {
        int k = kc * 32 + kg * 8;
        half8 af[4], bf[4];
        #pragma unroll
        for (int i = 0; i < 4; ++i)
            af[i] = *(const half8*)&A[(size_t)(m0 + i * 16 + fr) * K + k];
        #pragma unroll
        for (int j = 0; j < 4; ++j)
            bf[j] = *(const half8*)&W[(size_t)(n0 + j * 16 + fr) * K + k];
        #pragma unroll
        for (int i = 0; i < 4; ++i)
            #pragma unroll
            for (int j = 0; j < 4; ++j)
                acc[i][j] = __builtin_amdgcn_mfma_f32_16x16x32_f16(
                    af[i], bf[j], acc[i][j], 0, 0, 0);
    }

    #pragma unroll
    for (int i = 0; i < 4; ++i) {
        #pragma unroll
        for (int r = 0; r < 4; ++r) {
            int m = m0 + i * 16 + (l >> 4) * 4 + r;
            int t = m & (TLEN - 1);
            int b = m >> 9;
            _Float16* dst = &Cw[((size_t)t * BATCH + b) * G2];
            #pragma unroll
            for (int j = 0; j < 4; ++j)
                dst[n0 + j * 16 + (l & 15)] = (_Float16)acc[i][j][r];
        }
    }
}

// ---------------------------------------------------------------------------
// Agent-scope (device-coherent) helpers: sc0 sc1, bypass L1/per-XCD L2.
// ---------------------------------------------------------------------------
__device__ __forceinline__ void st_flag(int* p, int v) {
    __hip_atomic_store(p, v, __ATOMIC_RELAXED, __HIP_MEMORY_SCOPE_AGENT);
}
__device__ __forceinline__ unsigned long long ld_flag2(const int* p) {
    return __hip_atomic_load((const unsigned long long*)p, __ATOMIC_RELAXED,
                             __HIP_MEMORY_SCOPE_AGENT);
}
__device__ __forceinline__ unsigned long long ld_h2u(const unsigned short* p) {
    return __hip_atomic_load((const unsigned long long*)p, __ATOMIC_RELAXED,
                             __HIP_MEMORY_SCOPE_AGENT);
}
__device__ __forceinline__ void st_h32(unsigned int* p, unsigned int v) {
    __hip_atomic_store(p, v, __ATOMIC_RELAXED, __HIP_MEMORY_SCOPE_AGENT);
}

#define NWG 256
#define FSTRIDE 16   // flag-pairs 64 B apart (2 ints used per WG)
#define BT 8         // batches per WG
#define JT 16        // a-rows per WG (plus JT z-rows)

__global__ void rec_init(unsigned short* h0, int* flags) {
    int i = blockIdx.x * 256 + threadIdx.x;
    if (i < BHID) h0[i] = 0;              // fp16 +0.0
    if (i < NWG * FSTRIDE) flags[i] = 0;
}

// ---------------------------------------------------------------------------
// MFMA recurrence -- R15 structure with barriers A and C removed:
// 256 WGs x 512 thr (8 waves); bt = wg&3 (4 sync groups x 64 WGs); WG owns
// 16 j-rows (a+z) x 8 batches; wave wv = K-chunks wv*4..wv*4+3; A-frags in
// registers; B-frags = coherent 8B loads from the fp16 3-ring; C partials
// through red[8][32][17] LDS; gates on tid<128 (waves 0-1).
//
// Sync (new): TWO flags per WG, one per GATE WAVE, packed in one 64B line.
//  - publish: each gate wave stores its h-slice, drains its OWN vmcnt(0),
//    lane 0 posts its flag. No block barrier (was barrier C).
//  - consume: EVERY wave polls the group's 64 flag-pairs (one 8B load per
//    lane) before its B-loads. No broadcast barrier (was barrier A).
//  - barrier B (pre-gate reduce) is the only block barrier left.
// red single-buffer WAR-safe: any wave's red-write at t+1 is gated by its
// poll on both gate flags >= t+1, posted only after gates consumed red(t).
// ---------------------------------------------------------------------------
__global__ __launch_bounds__(512, 1)
void ligru_rec(const _Float16* __restrict__ w16,   // [T][B][2H] fp16
               const _Float16* __restrict__ U16,   // [2H][H] fp16
               unsigned short* __restrict__ hring, // [3][B][H] fp16 ring
               int* __restrict__ flags,            // NWG flag-pairs
               float* __restrict__ out32,          // [B][T][H] fp32 (layer 1)
               _Float16* __restrict__ act16,       // [B][T][H] fp16 (layer 0)
               float* __restrict__ hlast) {        // [B][H] fp32
    __shared__ float red[8][32][17];               // wave C partials (17 KB)

    const int wg  = blockIdx.x;
    const int tid = threadIdx.x;
    const int bt  = wg & 3;
    const int jb  = wg >> 2;          // 0..63
    const int j0  = jb * JT;
    const int bg0 = bt * BT;

    const int wv   = tid >> 6;        // wave 0..7: K-chunks wv*4..wv*4+3
    const int l    = tid & 63;
    const int mrow = l & 15;          // A-frag M row
    const int kg   = l >> 4;          // k-group (8 halves)
    const int bcol = bg0 + (l & 7);   // B-frag batch (cols 8-15 duplicate)

    // ---- A frags from preconverted fp16 U (8 frags = 32 VGPR)
    half8 Aa[4], Az[4];
    #pragma unroll
    for (int kc = 0; kc < 4; ++kc) {
        int k0 = (wv * 4 + kc) * 32 + kg * 8;
        Aa[kc] = *(const half8*)&U16[(size_t)(j0 + mrow) * HID + k0];
        Az[kc] = *(const half8*)&U16[(size_t)(HID + j0 + mrow) * HID + k0];
    }

    unsigned short* h_t = hring;
    unsigned short* h_n = hring + BHID;
    unsigned short* h_p = hring + 2 * BHID;

    // per-lane poll target: the group's l-th WG's flag pair (one 8B load)
    const int* pollp = &flags[(((l << 2) + bt)) * FSTRIDE];

    // gate coords (tid < 128): jl = row 0..15, bl = batch 0..7
    const int jl = tid & 15;
    const int bl = tid >> 4;
    const int bg = bg0 + bl;
    float hprev = 0.f;

    for (int t = 0; t < TLEN; ++t) {
        // ---- w prefetch (fp16, gate threads; issued before the poll)
        float wa = 0.f, wz = 0.f;
        if (tid < 128) {
            const _Float16* wt = &w16[((size_t)t * BATCH + bg) * G2];
            wa = (float)wt[j0 + jl];
            wz = (float)wt[HID + j0 + jl];
        }

        // ---- per-wave poll: both gate flags of the group's 64 WGs >= t
        if (t > 0) {
            unsigned long long v = ld_flag2(pollp);
            while ((int)(unsigned int)v < t ||
                   (int)(unsigned int)(v >> 32) < t) {
                __builtin_amdgcn_s_sleep(1);
                v = ld_flag2(pollp);
            }
        }

        // ---- B frags from coherent ring + MFMA (8 per wave)
        f32x4 ca = {0.f, 0.f, 0.f, 0.f};
        f32x4 cz = {0.f, 0.f, 0.f, 0.f};
        #pragma unroll
        for (int kc = 0; kc < 4; ++kc) {
            int k0 = (wv * 4 + kc) * 32 + kg * 8;
            const unsigned short* hp = &h_t[(size_t)bcol * HID + k0];
            union { unsigned long long u[2]; half8 h; } B;
            B.u[0] = ld_h2u(hp);
            B.u[1] = ld_h2u(hp + 4);
            ca = __builtin_amdgcn_mfma_f32_16x16x32_f16(Aa[kc], B.h, ca, 0, 0, 0);
            cz = __builtin_amdgcn_mfma_f32_16x16x32_f16(Az[kc], B.h, cz, 0, 0, 0);
        }

        // ---- C layout: col = l&15 (batch), row = (l>>4)*4 + r (j)
        #pragma unroll
        for (int r = 0; r < 4; ++r) {
            red[wv][kg * 4 + r][l & 15]      = ca[r];
            red[wv][16 + kg * 4 + r][l & 15] = cz[r];
        }
        __syncthreads();   // barrier B: the only block barrier per step

        // ---- gates + state update + per-wave publish (waves 0-1)
        if (tid < 128) {
            float sa = 0.f, sz = 0.f;
            #pragma unroll
            for (int v = 0; v < 8; ++v) {
                sa += red[v][jl][bl];
                sz += red[v][16 + jl][bl];
            }
            float at = wa + sa;
            float zt = wz + sz;
            zt = 1.f / (1.f + expf(-zt));
            float hc = tanhf(at);
            float hnew = zt * hprev + (1.f - zt) * hc;
            hprev = hnew;

            unsigned short h16 =
                __builtin_bit_cast(unsigned short, (_Float16)hnew);
            unsigned int other = __shfl_xor((unsigned int)h16, 1);
            unsigned int pk = ((jl & 1) == 0)
                ? ((unsigned int)h16 | (other << 16))
                : ((other) | ((unsigned int)h16 << 16));

            if (t < TLEN - 1) {
                // h publish first, then layer output
                if ((jl & 1) == 0)
                    st_h32((unsigned int*)&h_n[(size_t)bg * HID + j0 + jl], pk);
                if (act16) {
                    if ((jl & 1) == 0)
                        *(unsigned int*)&act16[((size_t)bg * TLEN + t) * HID
                                               + j0 + jl] = pk;
                } else {
                    out32[((size_t)bg * TLEN + t) * HID + j0 + jl] = hnew;
                }
                // per-gate-wave drain + flag (no block barrier)
                asm volatile("s_waitcnt vmcnt(0)" ::: "memory");
                if (l == 0)
                    st_flag(&flags[wg * FSTRIDE + wv], t + 1);
            } else {
                hlast[(size_t)bg * HID + j0 + jl] = hnew;
                if (act16) {
                    if ((jl & 1) == 0)
                        *(unsigned int*)&act16[((size_t)bg * TLEN + t) * HID
                                               + j0 + jl] = pk;
                } else {
                    out32[((size_t)bg * TLEN + t) * HID + j0 + jl] = hnew;
                }
            }
        }

        unsigned short* tmp = h_t; h_t = h_n; h_n = h_p; h_p = tmp;
    }
}

// ---------------------------------------------------------------------------
extern "C" void kernel_launch(void* const* d_in, const int* in_sizes, int n_in,
                              void* d_out, int out_size, void* d_ws, size_t ws_size,
                              hipStream_t stream) {
    (void)in_sizes; (void)n_in; (void)out_size; (void)ws_size;

    const float* x  = (const float*)d_in[0];
    const float* W0 = (const float*)d_in[1];
    const float* U0 = (const float*)d_in[2];
    const float* W1 = (const float*)d_in[3];
    const float* U1 = (const float*)d_in[4];

    float* out    = (float*)d_out;                              // [B,T,H]
    float* hstack = out + (size_t)BATCH * TLEN * HID;           // [2,B,H]

    // workspace layout
    int*            flags = (int*)d_ws;                               // 16 KB
    unsigned short* hring = (unsigned short*)(flags + NWG * FSTRIDE); // 192 KB
    _Float16*       W16   = (_Float16*)(hring + 3 * BHID);            // 4 MB
    _Float16*       U16   = W16 + (size_t)G2 * HID;                   // 4 MB
    _Float16*       xact  = U16 + (size_t)G2 * HID;                   // 32 MB
    _Float16*       wbuf  = xact + (size_t)BATCH * TLEN * HID;        // 64 MB

    dim3 gg(16384 / 128, 2048 / 128);
    int init_blocks = (BHID + 255) / 256;

    // ---- layer 0 ----
    conv_f16<<<(BATCH * TLEN * 512 / 8 + 255) / 256, 256, 0, stream>>>(
        x, xact, BATCH * TLEN * 512 / 8);
    conv_f16<<<(G2 * 512 / 8 + 255) / 256, 256, 0, stream>>>(
        W0, W16, G2 * 512 / 8);
    conv_f16<<<(G2 * HID / 8 + 255) / 256, 256, 0, stream>>>(
        U0, U16, G2 * HID / 8);
    proj_gemm_f16<<<gg, 256, 0, stream>>>(xact, W16, wbuf, 512);
    rec_init<<<init_blocks, 256, 0, stream>>>(hring, flags);
    ligru_rec<<<dim3(NWG), dim3(512), 0, stream>>>(
        wbuf, U16, hring, flags, nullptr, xact, hstack);  // fp16 act out

    // ---- layer 1 ----
    conv_f16<<<(G2 * HID / 8 + 255) / 256, 256, 0, stream>>>(
        W1, W16, G2 * HID / 8);
    conv_f16<<<(G2 * HID / 8 + 255) / 256, 256, 0, stream>>>(
        U1, U16, G2 * HID / 8);
    proj_gemm_f16<<<gg, 256, 0, stream>>>(xact, W16, wbuf, 1024);
    rec_init<<<init_blocks, 256, 0, stream>>>(hring, flags);
    ligru_rec<<<dim3(NWG), dim3(512), 0, stream>>>(
        wbuf, U16, hring, flags, out, nullptr, hstack + BHID);
}

// Round 17
// 3527.753 us; speedup vs baseline: 1.4891x; 1.4891x over previous
//
#include <hip/hip_runtime.h>
#include <math.h>

#define BATCH 32
#define TLEN  512
#define HID   1024
#define G2    2048   // 2*H
#define BHID (BATCH * HID)

typedef _Float16 half8 __attribute__((ext_vector_type(8)));
typedef float f32x4 __attribute__((ext_vector_type(4)));

// fast device math: v_exp_f32 / v_rcp_f32 (ulp-level, fine vs fp16 threshold)
#define LOG2E 1.44269504f
__device__ __forceinline__ float fast_sigmoid(float z) {
    return __builtin_amdgcn_rcpf(1.f + __builtin_amdgcn_exp2f(-LOG2E * z));
}
__device__ __forceinline__ float fast_tanh(float a) {
    return 1.f - 2.f * __builtin_amdgcn_rcpf(
        1.f + __builtin_amdgcn_exp2f(2.f * LOG2E * a));
}

// ---------------------------------------------------------------------------
// fp32 -> fp16 conversion (8 elems/thread)
// ---------------------------------------------------------------------------
__global__ __launch_bounds__(256)
void conv_f16(const float* __restrict__ s, _Float16* __restrict__ d, int n8) {
    int i = blockIdx.x * 256 + threadIdx.x;
    if (i < n8) {
        int base = i * 8;
        float4 v0 = *(const float4*)&s[base];
        float4 v1 = *(const float4*)&s[base + 4];
        half8 h;
        h[0] = (_Float16)v0.x; h[1] = (_Float16)v0.y;
        h[2] = (_Float16)v0.z; h[3] = (_Float16)v0.w;
        h[4] = (_Float16)v1.x; h[5] = (_Float16)v1.y;
        h[6] = (_Float16)v1.z; h[7] = (_Float16)v1.w;
        *(half8*)&d[base] = h;
    }
}

// ---------------------------------------------------------------------------
// MFMA projection GEMM (proven R11-R15): Cw[t][b][n] = sum_k A[m][k]*W[n][k],
// m = b*T + t. fp16 in, fp16 out.
// ---------------------------------------------------------------------------
__global__ __launch_bounds__(256)
void proj_gemm_f16(const _Float16* __restrict__ A, const _Float16* __restrict__ W,
                   _Float16* __restrict__ Cw, int K) {
    const int tid = threadIdx.x;
    const int wv = tid >> 6;
    const int l  = tid & 63;
    const int m0 = blockIdx.x * 128 + (wv >> 1) * 64;
    const int n0 = blockIdx.y * 128 + (wv & 1) * 64;
    const int fr = l & 15;
    const int kg = l >> 4;

    f32x4 acc[4][4];
    #pragma unroll
    for (int i = 0; i < 4; ++i)
        #pragma unroll
        for (int j = 0; j < 4; ++j) acc[i][j] = (f32x4){0.f, 0.f, 0.f, 0.f};

    const int nkc = K >> 5;
    #pragma unroll 2
    for (int kc = 0; kc < nkc; ++kc) {
        int k = kc * 32 + kg * 8;
        half8 af[4], bf[4];
        #pragma unroll
        for (int i = 0; i < 4; ++i)
            af[i] = *(const half8*)&A[(size_t)(m0 + i * 16 + fr) * K + k];
        #pragma unroll
        for (int j = 0; j < 4; ++j)
            bf[j] = *(const half8*)&W[(size_t)(n0 + j * 16 + fr) * K + k];
        #pragma unroll
        for (int i = 0; i < 4; ++i)
            #pragma unroll
            for (int j = 0; j < 4; ++j)
                acc[i][j] = __builtin_amdgcn_mfma_f32_16x16x32_f16(
                    af[i], bf[j], acc[i][j], 0, 0, 0);
    }

    #pragma unroll
    for (int i = 0; i < 4; ++i) {
        #pragma unroll
        for (int r = 0; r < 4; ++r) {
            int m = m0 + i * 16 + (l >> 4) * 4 + r;
            int t = m & (TLEN - 1);
            int b = m >> 9;
            _Float16* dst = &Cw[((size_t)t * BATCH + b) * G2];
            #pragma unroll
            for (int j = 0; j < 4; ++j)
                dst[n0 + j * 16 + (l & 15)] = (_Float16)acc[i][j][r];
        }
    }
}

// ---------------------------------------------------------------------------
// Agent-scope (device-coherent) helpers: sc0 sc1, bypass L1/per-XCD L2.
// ---------------------------------------------------------------------------
__device__ __forceinline__ void st_flag(int* p, int v) {
    __hip_atomic_store(p, v, __ATOMIC_RELAXED, __HIP_MEMORY_SCOPE_AGENT);
}
__device__ __forceinline__ int ld_flag(const int* p) {
    return __hip_atomic_load(p, __ATOMIC_RELAXED, __HIP_MEMORY_SCOPE_AGENT);
}
__device__ __forceinline__ unsigned long long ld_h2u(const unsigned short* p) {
    return __hip_atomic_load((const unsigned long long*)p, __ATOMIC_RELAXED,
                             __HIP_MEMORY_SCOPE_AGENT);
}
__device__ __forceinline__ void st_h32(unsigned int* p, unsigned int v) {
    __hip_atomic_store(p, v, __ATOMIC_RELAXED, __HIP_MEMORY_SCOPE_AGENT);
}

#define NWG 256
#define FSTRIDE 16   // flags 64 B apart
#define BT 8         // batches per WG
#define JT 16        // a-rows per WG (plus JT z-rows)

__global__ void rec_init(unsigned short* h0, int* flags) {
    int i = blockIdx.x * 256 + threadIdx.x;
    if (i < BHID) h0[i] = 0;              // fp16 +0.0
    if (i < NWG * FSTRIDE) flags[i] = 0;
}

// ---------------------------------------------------------------------------
// MFMA recurrence -- R15's verified structure (R10 skeleton + f16 w/U):
// 256 WGs x 512 thr (8 waves); bt = wg&3 (4 sync groups x 64 WGs); WG owns
// 16 j-rows (a+z) x 8 batches; wave wv = K-chunks wv*4..wv*4+3; A-frags in
// registers; B-frags = coherent 8B loads from the fp16 3-ring; C partials
// through LDS; gates on tid<128; 3 barriers/step; publish = packed coherent
// h-store + barrier-C drain + per-WG flag; poll = 64 flags (tid<64).
// R17 micro-deltas ONLY:
//  (1) red padded [8][32][20]: write aliasing 4-way -> 2-way (free, m136).
//  (2) fast sigmoid/tanh via v_exp_f32 + v_rcp_f32.
//  (3) out/act store moved AFTER the flag post -- only h-stores gate
//      consumers, so the output store's drain leaves the critical path.
// ---------------------------------------------------------------------------
__global__ __launch_bounds__(512, 1)
void ligru_rec(const _Float16* __restrict__ w16,   // [T][B][2H] fp16
               const _Float16* __restrict__ U16,   // [2H][H] fp16
               unsigned short* __restrict__ hring, // [3][B][H] fp16 ring
               int* __restrict__ flags,            // NWG*FSTRIDE, pre-zeroed
               float* __restrict__ out32,          // [B][T][H] fp32 (layer 1)
               _Float16* __restrict__ act16,       // [B][T][H] fp16 (layer 0)
               float* __restrict__ hlast) {        // [B][H] fp32
    __shared__ float red[8][32][20];               // wave C partials (20 KB)

    const int wg  = blockIdx.x;
    const int tid = threadIdx.x;
    const int bt  = wg & 3;
    const int jb  = wg >> 2;          // 0..63
    const int j0  = jb * JT;
    const int bg0 = bt * BT;

    const int wv   = tid >> 6;        // wave 0..7: K-chunks wv*4..wv*4+3
    const int l    = tid & 63;
    const int mrow = l & 15;          // A-frag M row
    const int kg   = l >> 4;          // k-group (8 halves)
    const int bcol = bg0 + (l & 7);   // B-frag batch (cols 8-15 duplicate)

    // ---- A frags from preconverted fp16 U (8 frags = 32 VGPR)
    half8 Aa[4], Az[4];
    #pragma unroll
    for (int kc = 0; kc < 4; ++kc) {
        int k0 = (wv * 4 + kc) * 32 + kg * 8;
        Aa[kc] = *(const half8*)&U16[(size_t)(j0 + mrow) * HID + k0];
        Az[kc] = *(const half8*)&U16[(size_t)(HID + j0 + mrow) * HID + k0];
    }

    unsigned short* h_t = hring;
    unsigned short* h_n = hring + BHID;
    unsigned short* h_p = hring + 2 * BHID;

    // gate coords (tid < 128): jl = row 0..15, bl = batch 0..7
    const int jl = tid & 15;
    const int bl = tid >> 4;
    const int bg = bg0 + bl;
    float hprev = 0.f;

    for (int t = 0; t < TLEN; ++t) {
        // ---- w prefetch (fp16, gate threads; issued before the poll)
        float wa = 0.f, wz = 0.f;
        if (tid < 128) {
            const _Float16* wt = &w16[((size_t)t * BATCH + bg) * G2];
            wa = (float)wt[j0 + jl];
            wz = (float)wt[HID + j0 + jl];
        }

        // ---- wait for the 64 group peers to have published h(t)
        if (t > 0) {
            if (tid < 64) {
                const int* fp = &flags[((tid << 2) + bt) * FSTRIDE];
                while (ld_flag(fp) < t)
                    __builtin_amdgcn_s_sleep(1);
            }
            __syncthreads();   // barrier A
        }

        // ---- B frags from coherent ring + MFMA (8 per wave)
        f32x4 ca = {0.f, 0.f, 0.f, 0.f};
        f32x4 cz = {0.f, 0.f, 0.f, 0.f};
        #pragma unroll
        for (int kc = 0; kc < 4; ++kc) {
            int k0 = (wv * 4 + kc) * 32 + kg * 8;
            const unsigned short* hp = &h_t[(size_t)bcol * HID + k0];
            union { unsigned long long u[2]; half8 h; } B;
            B.u[0] = ld_h2u(hp);
            B.u[1] = ld_h2u(hp + 4);
            ca = __builtin_amdgcn_mfma_f32_16x16x32_f16(Aa[kc], B.h, ca, 0, 0, 0);
            cz = __builtin_amdgcn_mfma_f32_16x16x32_f16(Az[kc], B.h, cz, 0, 0, 0);
        }

        // ---- C layout: col = l&15 (batch), row = (l>>4)*4 + r (j)
        #pragma unroll
        for (int r = 0; r < 4; ++r) {
            red[wv][kg * 4 + r][l & 15]      = ca[r];
            red[wv][16 + kg * 4 + r][l & 15] = cz[r];
        }
        __syncthreads();   // barrier B: partials complete

        // ---- gates + state update (128 threads)
        unsigned int pk = 0;
        float hnew = 0.f;
        if (tid < 128) {
            float sa = 0.f, sz = 0.f;
            #pragma unroll
            for (int v = 0; v < 8; ++v) {
                sa += red[v][jl][bl];
                sz += red[v][16 + jl][bl];
            }
            float at = wa + sa;
            float zt = fast_sigmoid(wz + sz);
            float hc = fast_tanh(at);
            hnew = zt * hprev + (1.f - zt) * hc;
            hprev = hnew;

            unsigned short h16 =
                __builtin_bit_cast(unsigned short, (_Float16)hnew);
            unsigned int other = __shfl_xor((unsigned int)h16, 1);
            pk = ((jl & 1) == 0)
                ? ((unsigned int)h16 | (other << 16))
                : ((other) | ((unsigned int)h16 << 16));

            // h publish ONLY (keeps the pre-flag drain minimal)
            if (t < TLEN - 1) {
                if ((jl & 1) == 0)
                    st_h32((unsigned int*)&h_n[(size_t)bg * HID + j0 + jl], pk);
            } else {
                hlast[(size_t)bg * HID + j0 + jl] = hnew;
            }
        }

        // ---- publish barrier + flag, THEN the layer output store
        if (t < TLEN - 1) {
            __syncthreads();   // barrier C: drains vmcnt -> h stores at LLC
            if (tid == 0) st_flag(&flags[wg * FSTRIDE], t + 1);
        }
        if (tid < 128) {
            if (act16) {
                if ((jl & 1) == 0)
                    *(unsigned int*)&act16[((size_t)bg * TLEN + t) * HID
                                           + j0 + jl] = pk;
            } else {
                out32[((size_t)bg * TLEN + t) * HID + j0 + jl] = hnew;
            }
        }

        unsigned short* tmp = h_t; h_t = h_n; h_n = h_p; h_p = tmp;
    }
}

// ---------------------------------------------------------------------------
extern "C" void kernel_launch(void* const* d_in, const int* in_sizes, int n_in,
                              void* d_out, int out_size, void* d_ws, size_t ws_size,
                              hipStream_t stream) {
    (void)in_sizes; (void)n_in; (void)out_size; (void)ws_size;

    const float* x  = (const float*)d_in[0];
    const float* W0 = (const float*)d_in[1];
    const float* U0 = (const float*)d_in[2];
    const float* W1 = (const float*)d_in[3];
    const float* U1 = (const float*)d_in[4];

    float* out    = (float*)d_out;                              // [B,T,H]
    float* hstack = out + (size_t)BATCH * TLEN * HID;           // [2,B,H]

    // workspace layout
    int*            flags = (int*)d_ws;                               // 16 KB
    unsigned short* hring = (unsigned short*)(flags + NWG * FSTRIDE); // 192 KB
    _Float16*       W16   = (_Float16*)(hring + 3 * BHID);            // 4 MB
    _Float16*       U16   = W16 + (size_t)G2 * HID;                   // 4 MB
    _Float16*       xact  = U16 + (size_t)G2 * HID;                   // 32 MB
    _Float16*       wbuf  = xact + (size_t)BATCH * TLEN * HID;        // 64 MB

    dim3 gg(16384 / 128, 2048 / 128);
    int init_blocks = (BHID + 255) / 256;

    // ---- layer 0 ----
    conv_f16<<<(BATCH * TLEN * 512 / 8 + 255) / 256, 256, 0, stream>>>(
        x, xact, BATCH * TLEN * 512 / 8);
    conv_f16<<<(G2 * 512 / 8 + 255) / 256, 256, 0, stream>>>(
        W0, W16, G2 * 512 / 8);
    conv_f16<<<(G2 * HID / 8 + 255) / 256, 256, 0, stream>>>(
        U0, U16, G2 * HID / 8);
    proj_gemm_f16<<<gg, 256, 0, stream>>>(xact, W16, wbuf, 512);
    rec_init<<<init_blocks, 256, 0, stream>>>(hring, flags);
    ligru_rec<<<dim3(NWG), dim3(512), 0, stream>>>(
        wbuf, U16, hring, flags, nullptr, xact, hstack);  // fp16 act out

    // ---- layer 1 ----
    conv_f16<<<(G2 * HID / 8 + 255) / 256, 256, 0, stream>>>(
        W1, W16, G2 * HID / 8);
    conv_f16<<<(G2 * HID / 8 + 255) / 256, 256, 0, stream>>>(
        U1, U16, G2 * HID / 8);
    proj_gemm_f16<<<gg, 256, 0, stream>>>(xact, W16, wbuf, 1024);
    rec_init<<<init_blocks, 256, 0, stream>>>(hring, flags);
    ligru_rec<<<dim3(NWG), dim3(512), 0, stream>>>(
        wbuf, U16, hring, flags, out, nullptr, hstack + BHID);
}